// Round 6
// baseline (809.558 us; speedup 1.0000x reference)
//
#include <hip/hip_runtime.h>
#include <float.h>

#define NN 100000
#define NE 1600000
#define IND 128
#define NH 4
#define TOT 64
#define NCOL 144                 // 64 h | 64 res | 4 al | 4 ar | 8 pad
#define BKT 782                  // ceil(NN/128): buckets of 128 dst nodes
#define STRIPES 8                // XCD stripes per bucket
#define CAPS 512                 // per (bucket,stripe) record capacity (mean 256, 16 sigma)
#define CHUNK 8192               // edges per kbin2 block
#define NBIN ((NE + CHUNK - 1) / CHUNK)   // 196

typedef __attribute__((ext_vector_type(8))) short short8;
typedef __attribute__((ext_vector_type(4))) float f32x4;

__device__ __forceinline__ float lrelu(float a) { return a > 0.0f ? a : 0.2f * a; }

__device__ __forceinline__ unsigned short bf16_rne(float f) {
    unsigned u = __float_as_uint(f);
    unsigned r = u + 0x7FFFu + ((u >> 16) & 1u);
    return (unsigned short)(r >> 16);
}
__device__ __forceinline__ float bf16_to_f(unsigned short h) {
    return __uint_as_float(((unsigned)h) << 16);
}

// K0: build split-bf16 transposed weights WT[c][k], c in [0,144)
__global__ void k0_wt(const float* __restrict__ lw, const float* __restrict__ lrw,
                      const float* __restrict__ attl, const float* __restrict__ attr,
                      unsigned short* __restrict__ WTh, unsigned short* __restrict__ WTl) {
    int idx = blockIdx.x * 256 + threadIdx.x;   // NCOL*128 = 18432
    if (idx >= NCOL * 128) return;
    int c = idx >> 7, k = idx & 127;
    float v = 0.f;
    if (c < 64) v = lw[k * 64 + c];
    else if (c < 128) v = lrw[k * 64 + (c - 64)];
    else if (c < 132) {
        int hh = c - 128; float s = 0.f;
        #pragma unroll
        for (int j = 0; j < 16; ++j) s += lw[k * 64 + hh * 16 + j] * attl[hh * 16 + j];
        v = s;
    } else if (c < 136) {
        int hh = c - 132; float s = 0.f;
        #pragma unroll
        for (int j = 0; j < 16; ++j) s += lw[k * 64 + hh * 16 + j] * attr[hh * 16 + j];
        v = s;
    }
    unsigned short hi = bf16_rne(v);
    float hif = bf16_to_f(hi);
    WTh[idx] = hi;
    WTl[idx] = bf16_rne(v - hif);
}

// K1: MFMA GEMM, x[100000x128] @ WT^T[128x144] via split-bf16 (3 mfma per tile)
__global__ __launch_bounds__(256) void k1_mfma(const float* __restrict__ x,
        const unsigned short* __restrict__ WTh, const unsigned short* __restrict__ WTl,
        unsigned short* __restrict__ hbf, float* __restrict__ res,
        float* __restrict__ al, float* __restrict__ ar) {
    int lane = threadIdx.x & 63;
    int wave = threadIdx.x >> 6;
    int row0 = blockIdx.x * 128 + wave * 32;
    int lr = lane & 15;     // A-row / B-col / C-col within tile
    int lk = lane >> 4;     // k-group (0..3)

    f32x4 acc[2][9];
    #pragma unroll
    for (int mt = 0; mt < 2; ++mt)
        #pragma unroll
        for (int nt = 0; nt < 9; ++nt) acc[mt][nt] = (f32x4)(0.f);

    #pragma unroll
    for (int ks = 0; ks < 4; ++ks) {
        int k0 = ks * 32 + lk * 8;
        short8 bh[9], bl[9];
        #pragma unroll
        for (int nt = 0; nt < 9; ++nt) {
            bh[nt] = *(const short8*)(WTh + (size_t)(nt * 16 + lr) * 128 + k0);
            bl[nt] = *(const short8*)(WTl + (size_t)(nt * 16 + lr) * 128 + k0);
        }
        #pragma unroll
        for (int mt = 0; mt < 2; ++mt) {
            int row = row0 + mt * 16 + lr;
            float4 v0 = make_float4(0.f, 0.f, 0.f, 0.f), v1 = v0;
            if (row < NN) {
                v0 = *(const float4*)(x + (size_t)row * IND + k0);
                v1 = *(const float4*)(x + (size_t)row * IND + k0 + 4);
            }
            float vs[8] = {v0.x, v0.y, v0.z, v0.w, v1.x, v1.y, v1.z, v1.w};
            short8 ah, alo;
            #pragma unroll
            for (int i = 0; i < 8; ++i) {
                unsigned short hi = bf16_rne(vs[i]);
                ah[i] = (short)hi;
                alo[i] = (short)bf16_rne(vs[i] - bf16_to_f(hi));
            }
            #pragma unroll
            for (int nt = 0; nt < 9; ++nt) {
                acc[mt][nt] = __builtin_amdgcn_mfma_f32_16x16x32_bf16(ah, bh[nt], acc[mt][nt], 0, 0, 0);
                acc[mt][nt] = __builtin_amdgcn_mfma_f32_16x16x32_bf16(alo, bh[nt], acc[mt][nt], 0, 0, 0);
                acc[mt][nt] = __builtin_amdgcn_mfma_f32_16x16x32_bf16(ah, bl[nt], acc[mt][nt], 0, 0, 0);
            }
        }
    }
    #pragma unroll
    for (int mt = 0; mt < 2; ++mt) {
        #pragma unroll
        for (int nt = 0; nt < 9; ++nt) {
            int c = nt * 16 + lr;
            #pragma unroll
            for (int r = 0; r < 4; ++r) {
                int row = row0 + mt * 16 + lk * 4 + r;
                if (row >= NN) continue;
                float v = acc[mt][nt][r];
                if (c < 64)       hbf[(size_t)row * TOT + c] = bf16_rne(v);
                else if (c < 128) res[(size_t)row * TOT + (c - 64)] = v;
                else if (c < 132) al[(size_t)row * 4 + (c - 128)] = v;
                else if (c < 136) ar[(size_t)row * 4 + (c - 132)] = v;
            }
        }
    }
}

// kbin2: chunked counting-append. Each block owns CHUNK edges: LDS histogram over
// the 782 buckets -> one global atomicAdd per nonempty bucket reserves a RUN
// (mean 10.5 records = 84B) in that bucket's stripe region -> re-read chunk and
// write records into the run. Long runs -> full-line writebacks.
__global__ __launch_bounds__(512) void kbin2(const int* __restrict__ src,
                                             const int* __restrict__ dst,
                                             const float* __restrict__ ew,
                                             int* __restrict__ cursor,
                                             int2* __restrict__ tmp) {
    __shared__ int hist[BKT];
    __shared__ int lcur[BKT];
    int tid = threadIdx.x;
    int stripe = blockIdx.x & 7;
    int e0 = blockIdx.x * CHUNK;
    for (int i = tid; i < BKT; i += 512) hist[i] = 0;
    __syncthreads();
    for (int i = tid; i < CHUNK; i += 512) {
        int e = e0 + i;
        if (e < NE) atomicAdd(&hist[dst[e] >> 7], 1);
    }
    __syncthreads();
    for (int b = tid; b < BKT; b += 512) {
        int c = hist[b];
        lcur[b] = (c > 0) ? atomicAdd(cursor + b * STRIPES + stripe, c) : 0;
    }
    __syncthreads();
    for (int i = tid; i < CHUNK; i += 512) {
        int e = e0 + i;
        if (e >= NE) continue;
        int d = dst[e];
        int b = d >> 7;
        int pos = atomicAdd(&lcur[b], 1);
        if (pos < CAPS)
            tmp[(size_t)(b * STRIPES + stripe) * CAPS + pos] =
                make_int2(src[e] | ((d & 127) << 20), __float_as_int(ew[e]));
    }
}

// kagg2: one block per 128-node bucket. Read the bucket's records sequentially,
// accumulate softmax numerator/denominator in LDS (f32), then normalize + ELU +
// residual (already in out). Replaces kdeg + 3 scans + kperm + CSR kagg.
__global__ __launch_bounds__(256) void kagg2(const int* __restrict__ cursor,
                                             const int2* __restrict__ tmp,
                                             const float* __restrict__ al,
                                             const float* __restrict__ ar,
                                             const unsigned short* __restrict__ hbf,
                                             float* __restrict__ out) {
    __shared__ float accN[128][65];   // pad 65: spreads part*4 bank pattern by dlo
    __shared__ float accD[128][4];
    __shared__ float arp[128][4];
    int tid = threadIdx.x;
    int b = blockIdx.x;
    int node0 = b * 128;
    int nvalid = min(128, NN - node0);          // last bucket is partial

    for (int i = tid; i < 128 * 65; i += 256) ((float*)accN)[i] = 0.f;
    for (int i = tid; i < 128 * 4; i += 256) {
        ((float*)accD)[i] = 0.f;
        ((float*)arp)[i] = (i < nvalid * 4) ? ar[(size_t)node0 * 4 + i] : 0.f;
    }
    __syncthreads();

    int rl = tid >> 4;        // record lane group 0..15
    int part = tid & 15;      // 4 floats of h per part
    int head = part >> 2;

    for (int s = 0; s < STRIPES; ++s) {
        int sb = b * STRIPES + s;
        int n = min(cursor[sb], CAPS);
        const int2* tp = tmp + (size_t)sb * CAPS;
        for (int i = rl; i < n; i += 16) {
            int2 r = tp[i];                              // broadcast across 16 lanes
            int sn = r.x & 0xFFFFF;
            int dlo = ((unsigned)r.x) >> 20;
            float w = __int_as_float(r.y);
            float a = lrelu(w * (al[(size_t)sn * 4 + head] + arp[dlo][head]));
            float c = __expf(a);
            uint2 u = *(const uint2*)(hbf + (size_t)sn * TOT + part * 4);
            atomicAdd(&accN[dlo][part * 4 + 0], __uint_as_float(u.x << 16) * c);
            atomicAdd(&accN[dlo][part * 4 + 1], __uint_as_float(u.x & 0xFFFF0000u) * c);
            atomicAdd(&accN[dlo][part * 4 + 2], __uint_as_float(u.y << 16) * c);
            atomicAdd(&accN[dlo][part * 4 + 3], __uint_as_float(u.y & 0xFFFF0000u) * c);
            if ((part & 3) == 0) atomicAdd(&accD[dlo][head], c);
        }
    }
    __syncthreads();

    // epilogue: 128 nodes x 16 parts = 2048 items
    for (int idx = tid; idx < 128 * 16; idx += 256) {
        int nl = idx >> 4;
        if (nl >= nvalid) break;
        int pp = idx & 15;
        float den = accD[nl][pp >> 2];
        float rinv = (den > 0.f) ? 1.f / den : 0.f;
        float* op = out + (size_t)(node0 + nl) * TOT + pp * 4;
        float4 rr = *(const float4*)op;
        float4 o;
        float a0 = accN[nl][pp * 4 + 0] * rinv;
        float a1 = accN[nl][pp * 4 + 1] * rinv;
        float a2 = accN[nl][pp * 4 + 2] * rinv;
        float a3 = accN[nl][pp * 4 + 3] * rinv;
        o.x = (a0 > 0.f ? a0 : expm1f(a0)) + rr.x;
        o.y = (a1 > 0.f ? a1 : expm1f(a1)) + rr.y;
        o.z = (a2 > 0.f ? a2 : expm1f(a2)) + rr.z;
        o.w = (a3 > 0.f ? a3 : expm1f(a3)) + rr.w;
        *(float4*)op = o;
    }
}

extern "C" void kernel_launch(void* const* d_in, const int* in_sizes, int n_in,
                              void* d_out, int out_size, void* d_ws, size_t ws_size,
                              hipStream_t stream) {
    const float* x    = (const float*)d_in[0];
    const int*   ei   = (const int*)d_in[1];
    const float* ew   = (const float*)d_in[2];
    const float* lw   = (const float*)d_in[3];
    const float* attl = (const float*)d_in[4];
    const float* attr = (const float*)d_in[5];
    const float* lrw  = (const float*)d_in[6];
    float* out = (float*)d_out;
    const int* src = ei;
    const int* dst = ei + NE;

    char* w = (char*)d_ws;
    auto alloc = [&](size_t bytes) { char* p = w; w += (bytes + 255) & ~(size_t)255; return p; };
    unsigned short* WTh = (unsigned short*)alloc((size_t)NCOL * 128 * 2);
    unsigned short* WTl = (unsigned short*)alloc((size_t)NCOL * 128 * 2);
    unsigned short* hbf = (unsigned short*)alloc((size_t)NN * TOT * 2);
    float* al     = (float*)alloc((size_t)NN * 4 * 4);
    float* ar     = (float*)alloc((size_t)NN * 4 * 4);
    int*   cursor = (int*)alloc((size_t)BKT * STRIPES * 4);
    int2*  tmp    = (int2*)alloc((size_t)BKT * STRIPES * CAPS * 8);
    size_t needed = (size_t)(w - (char*)d_ws);
    if (ws_size < needed) return;  // fail loudly (validation will catch)

    hipMemsetAsync(cursor, 0, (size_t)BKT * STRIPES * 4, stream);

    k0_wt<<<(NCOL * 128 + 255) / 256, 256, 0, stream>>>(lw, lrw, attl, attr, WTh, WTl);
    k1_mfma<<<(NN + 127) / 128, 256, 0, stream>>>(x, WTh, WTl, hbf, out, al, ar);
    kbin2<<<NBIN, 512, 0, stream>>>(src, dst, ew, cursor, tmp);
    kagg2<<<BKT, 256, 0, stream>>>(cursor, tmp, al, ar, hbf, out);
}

// Round 7
// 176.506 us; speedup vs baseline: 4.5866x; 4.5866x over previous
//
#include <hip/hip_runtime.h>
#include <float.h>

#define NN 100000
#define NE 1600000
#define IND 128
#define NH 4
#define TOT 64
#define NCOL 144                 // 64 h | 64 res | 4 al | 4 ar | 8 pad
#define NB ((NN + 255) / 256)    // scan blocks (256-node granularity)
#define BKT 782                  // ceil(NN/128): buckets of 128 dst nodes
#define STRIPES 8                // XCD stripes per bucket
#define CAPS 512                 // per (bucket,stripe) record capacity (mean 256, 16 sigma)
#define CHUNK 8192               // edges per kbin2 block
#define NBIN ((NE + CHUNK - 1) / CHUNK)   // 196

typedef __attribute__((ext_vector_type(8))) short short8;
typedef __attribute__((ext_vector_type(4))) float f32x4;

__device__ __forceinline__ float lrelu(float a) { return a > 0.0f ? a : 0.2f * a; }

__device__ __forceinline__ unsigned short bf16_rne(float f) {
    unsigned u = __float_as_uint(f);
    unsigned r = u + 0x7FFFu + ((u >> 16) & 1u);
    return (unsigned short)(r >> 16);
}
__device__ __forceinline__ float bf16_to_f(unsigned short h) {
    return __uint_as_float(((unsigned)h) << 16);
}

// K0: build split-bf16 transposed weights WT[c][k], c in [0,144)
__global__ void k0_wt(const float* __restrict__ lw, const float* __restrict__ lrw,
                      const float* __restrict__ attl, const float* __restrict__ attr,
                      unsigned short* __restrict__ WTh, unsigned short* __restrict__ WTl) {
    int idx = blockIdx.x * 256 + threadIdx.x;   // NCOL*128 = 18432
    if (idx >= NCOL * 128) return;
    int c = idx >> 7, k = idx & 127;
    float v = 0.f;
    if (c < 64) v = lw[k * 64 + c];
    else if (c < 128) v = lrw[k * 64 + (c - 64)];
    else if (c < 132) {
        int hh = c - 128; float s = 0.f;
        #pragma unroll
        for (int j = 0; j < 16; ++j) s += lw[k * 64 + hh * 16 + j] * attl[hh * 16 + j];
        v = s;
    } else if (c < 136) {
        int hh = c - 132; float s = 0.f;
        #pragma unroll
        for (int j = 0; j < 16; ++j) s += lw[k * 64 + hh * 16 + j] * attr[hh * 16 + j];
        v = s;
    }
    unsigned short hi = bf16_rne(v);
    float hif = bf16_to_f(hi);
    WTh[idx] = hi;
    WTl[idx] = bf16_rne(v - hif);
}

// K1: MFMA GEMM, x[100000x128] @ WT^T[128x144] via split-bf16 (3 mfma per tile)
__global__ __launch_bounds__(256) void k1_mfma(const float* __restrict__ x,
        const unsigned short* __restrict__ WTh, const unsigned short* __restrict__ WTl,
        unsigned short* __restrict__ hbf, float* __restrict__ res,
        float* __restrict__ al, float* __restrict__ ar) {
    int lane = threadIdx.x & 63;
    int wave = threadIdx.x >> 6;
    int row0 = blockIdx.x * 128 + wave * 32;
    int lr = lane & 15;     // A-row / B-col / C-col within tile
    int lk = lane >> 4;     // k-group (0..3)

    f32x4 acc[2][9];
    #pragma unroll
    for (int mt = 0; mt < 2; ++mt)
        #pragma unroll
        for (int nt = 0; nt < 9; ++nt) acc[mt][nt] = (f32x4)(0.f);

    #pragma unroll
    for (int ks = 0; ks < 4; ++ks) {
        int k0 = ks * 32 + lk * 8;
        short8 bh[9], bl[9];
        #pragma unroll
        for (int nt = 0; nt < 9; ++nt) {
            bh[nt] = *(const short8*)(WTh + (size_t)(nt * 16 + lr) * 128 + k0);
            bl[nt] = *(const short8*)(WTl + (size_t)(nt * 16 + lr) * 128 + k0);
        }
        #pragma unroll
        for (int mt = 0; mt < 2; ++mt) {
            int row = row0 + mt * 16 + lr;
            float4 v0 = make_float4(0.f, 0.f, 0.f, 0.f), v1 = v0;
            if (row < NN) {
                v0 = *(const float4*)(x + (size_t)row * IND + k0);
                v1 = *(const float4*)(x + (size_t)row * IND + k0 + 4);
            }
            float vs[8] = {v0.x, v0.y, v0.z, v0.w, v1.x, v1.y, v1.z, v1.w};
            short8 ah, alo;
            #pragma unroll
            for (int i = 0; i < 8; ++i) {
                unsigned short hi = bf16_rne(vs[i]);
                ah[i] = (short)hi;
                alo[i] = (short)bf16_rne(vs[i] - bf16_to_f(hi));
            }
            #pragma unroll
            for (int nt = 0; nt < 9; ++nt) {
                acc[mt][nt] = __builtin_amdgcn_mfma_f32_16x16x32_bf16(ah, bh[nt], acc[mt][nt], 0, 0, 0);
                acc[mt][nt] = __builtin_amdgcn_mfma_f32_16x16x32_bf16(alo, bh[nt], acc[mt][nt], 0, 0, 0);
                acc[mt][nt] = __builtin_amdgcn_mfma_f32_16x16x32_bf16(ah, bl[nt], acc[mt][nt], 0, 0, 0);
            }
        }
    }
    #pragma unroll
    for (int mt = 0; mt < 2; ++mt) {
        #pragma unroll
        for (int nt = 0; nt < 9; ++nt) {
            int c = nt * 16 + lr;
            #pragma unroll
            for (int r = 0; r < 4; ++r) {
                int row = row0 + mt * 16 + lk * 4 + r;
                if (row >= NN) continue;
                float v = acc[mt][nt][r];
                if (c < 64)       hbf[(size_t)row * TOT + c] = bf16_rne(v);
                else if (c < 128) res[(size_t)row * TOT + (c - 64)] = v;
                else if (c < 132) al[(size_t)row * 4 + (c - 128)] = v;
                else if (c < 136) ar[(size_t)row * 4 + (c - 132)] = v;
            }
        }
    }
}

// kbin2: chunked counting-append. Each block owns CHUNK edges: LDS histogram over
// the 782 buckets -> one global atomicAdd per nonempty bucket reserves a RUN
// (mean ~10.5 records) in that bucket's stripe region -> re-read chunk (L2-hot)
// and write records into the run. Long runs -> full-line writebacks.
__global__ __launch_bounds__(512) void kbin2(const int* __restrict__ src,
                                             const int* __restrict__ dst,
                                             const float* __restrict__ ew,
                                             int* __restrict__ cursor,
                                             int2* __restrict__ tmp) {
    __shared__ int hist[BKT];
    __shared__ int lcur[BKT];
    int tid = threadIdx.x;
    int stripe = blockIdx.x & 7;
    int e0 = blockIdx.x * CHUNK;
    for (int i = tid; i < BKT; i += 512) hist[i] = 0;
    __syncthreads();
    for (int i = tid; i < CHUNK; i += 512) {
        int e = e0 + i;
        if (e < NE) atomicAdd(&hist[dst[e] >> 7], 1);
    }
    __syncthreads();
    for (int b = tid; b < BKT; b += 512) {
        int c = hist[b];
        lcur[b] = (c > 0) ? atomicAdd(cursor + b * STRIPES + stripe, c) : 0;
    }
    __syncthreads();
    for (int i = tid; i < CHUNK; i += 512) {
        int e = e0 + i;
        if (e >= NE) continue;
        int d = dst[e];
        int b = d >> 7;
        int pos = atomicAdd(&lcur[b], 1);
        if (pos < CAPS)
            tmp[(size_t)(b * STRIPES + stripe) * CAPS + pos] =
                make_int2(src[e] | ((d & 127) << 20), __float_as_int(ew[e]));
    }
}

// kdeg: per-node degree from sub-buckets via LDS histogram (no global atomics).
__global__ __launch_bounds__(256) void kdeg(const int* __restrict__ cursor,
                                            const int2* __restrict__ tmp,
                                            int* __restrict__ deg) {
    __shared__ int hist[128];
    int tid = threadIdx.x;
    if (tid < 128) hist[tid] = 0;
    __syncthreads();
    #pragma unroll
    for (int s8 = 0; s8 < STRIPES; ++s8) {
        int sb = blockIdx.x * STRIPES + s8;
        int n = min(cursor[sb], CAPS);
        const int2* tp = tmp + (size_t)sb * CAPS;
        for (int i = tid; i < n; i += 256)
            atomicAdd(&hist[((unsigned)tp[i].x) >> 20], 1);
    }
    __syncthreads();
    int node = blockIdx.x * 128 + tid;
    if (tid < 128 && node < NN) deg[node] = hist[tid];
}

__global__ void kscan_block(const int* __restrict__ deg, int* __restrict__ bsum) {
    __shared__ int s[256];
    int i = blockIdx.x * 256 + threadIdx.x;
    s[threadIdx.x] = (i < NN) ? deg[i] : 0;
    __syncthreads();
    for (int off = 128; off > 0; off >>= 1) {
        if (threadIdx.x < off) s[threadIdx.x] += s[threadIdx.x + off];
        __syncthreads();
    }
    if (threadIdx.x == 0) bsum[blockIdx.x] = s[0];
}

__global__ void kscan_top(int* __restrict__ bsum) {
    __shared__ int s[512];
    int v = (threadIdx.x < NB) ? bsum[threadIdx.x] : 0;
    s[threadIdx.x] = v;
    __syncthreads();
    for (int off = 1; off < 512; off <<= 1) {
        int tv = (threadIdx.x >= off) ? s[threadIdx.x - off] : 0;
        __syncthreads();
        s[threadIdx.x] += tv;
        __syncthreads();
    }
    if (threadIdx.x < NB) bsum[threadIdx.x] = s[threadIdx.x] - v;  // exclusive
}

__global__ void kscan_final(const int* __restrict__ deg, const int* __restrict__ bsum,
                            int* __restrict__ rowptr) {
    __shared__ int s[256];
    int i = blockIdx.x * 256 + threadIdx.x;
    int v = (i < NN) ? deg[i] : 0;
    s[threadIdx.x] = v;
    __syncthreads();
    for (int off = 1; off < 256; off <<= 1) {
        int tv = (threadIdx.x >= off) ? s[threadIdx.x - off] : 0;
        __syncthreads();
        s[threadIdx.x] += tv;
        __syncthreads();
    }
    if (i < NN) {
        int ex = bsum[blockIdx.x] + s[threadIdx.x] - v;
        rowptr[i] = ex;
        if (i == NN - 1) rowptr[NN] = ex + v;
    }
}

// kperm: scatter sub-bucket records into final CSR position. LDS cursors;
// write window per block ~ deg(128 nodes)*8B ~ 16KB -> L2-local full lines.
__global__ __launch_bounds__(256) void kperm(const int* __restrict__ cursor,
                                             const int2* __restrict__ tmp,
                                             const int* __restrict__ rowptr,
                                             int2* __restrict__ rec) {
    __shared__ int cur[128];
    int tid = threadIdx.x;
    int nb = blockIdx.x * 128;
    if (tid < 128) {
        int node = nb + tid;
        cur[tid] = (node < NN) ? rowptr[node] : 0;
    }
    __syncthreads();
    #pragma unroll
    for (int s8 = 0; s8 < STRIPES; ++s8) {
        int sb = blockIdx.x * STRIPES + s8;
        int n = min(cursor[sb], CAPS);
        const int2* tp = tmp + (size_t)sb * CAPS;
        for (int i = tid; i < n; i += 256) {
            int2 r = tp[i];
            int dlo = ((unsigned)r.x) >> 20;
            int pos = atomicAdd(&cur[dlo], 1);
            rec[pos] = make_int2(r.x & 0xFFFFF, r.y);
        }
    }
}

// Aggregate per node, SINGLE pass, register accumulation, no atomics:
// agg = sum(exp(a_e) * h[src_e]) / sum(exp(a_e))   (softmax shift-invariance,
// |a| <~ 4 so no max subtraction needed). Then ELU + residual (already in out).
__global__ __launch_bounds__(256) void kagg(const int* __restrict__ rowptr,
                                            const int2* __restrict__ rec,
                                            const float* __restrict__ al,
                                            const float* __restrict__ ar,
                                            const unsigned short* __restrict__ hbf,
                                            float* __restrict__ out) {
    int t = threadIdx.x;
    int node = blockIdx.x * 16 + (t >> 4);
    if (node >= NN) return;
    int part = t & 15;
    int head = part >> 2;
    int beg = rowptr[node], end = rowptr[node + 1];
    float arh = ar[(size_t)node * 4 + head];

    float4 acc = make_float4(0.f, 0.f, 0.f, 0.f);
    float den = 0.f;
    for (int p = beg; p < end; ++p) {
        int2 r = rec[p];                       // broadcast across 16 lanes
        int s = r.x;
        float w = __int_as_float(r.y);
        float a = lrelu(w * (al[(size_t)s * 4 + head] + arh));
        float c = __expf(a);
        den += c;
        uint2 u = *(const uint2*)(hbf + (size_t)s * TOT + part * 4);  // 4 bf16 = 8B
        float h0 = __uint_as_float(u.x << 16);
        float h1 = __uint_as_float(u.x & 0xFFFF0000u);
        float h2 = __uint_as_float(u.y << 16);
        float h3 = __uint_as_float(u.y & 0xFFFF0000u);
        acc.x = fmaf(h0, c, acc.x);
        acc.y = fmaf(h1, c, acc.y);
        acc.z = fmaf(h2, c, acc.z);
        acc.w = fmaf(h3, c, acc.w);
    }
    float rinv = (den > 0.f) ? 1.f / den : 0.f;
    acc.x *= rinv; acc.y *= rinv; acc.z *= rinv; acc.w *= rinv;

    float* op = out + (size_t)node * TOT + part * 4;
    float4 r = *(const float4*)op;
    float4 o;
    o.x = (acc.x > 0.f ? acc.x : expm1f(acc.x)) + r.x;
    o.y = (acc.y > 0.f ? acc.y : expm1f(acc.y)) + r.y;
    o.z = (acc.z > 0.f ? acc.z : expm1f(acc.z)) + r.z;
    o.w = (acc.w > 0.f ? acc.w : expm1f(acc.w)) + r.w;
    *(float4*)op = o;
}

extern "C" void kernel_launch(void* const* d_in, const int* in_sizes, int n_in,
                              void* d_out, int out_size, void* d_ws, size_t ws_size,
                              hipStream_t stream) {
    const float* x    = (const float*)d_in[0];
    const int*   ei   = (const int*)d_in[1];
    const float* ew   = (const float*)d_in[2];
    const float* lw   = (const float*)d_in[3];
    const float* attl = (const float*)d_in[4];
    const float* attr = (const float*)d_in[5];
    const float* lrw  = (const float*)d_in[6];
    float* out = (float*)d_out;
    const int* src = ei;
    const int* dst = ei + NE;

    char* w = (char*)d_ws;
    auto alloc = [&](size_t bytes) { char* p = w; w += (bytes + 255) & ~(size_t)255; return p; };
    unsigned short* WTh = (unsigned short*)alloc((size_t)NCOL * 128 * 2);
    unsigned short* WTl = (unsigned short*)alloc((size_t)NCOL * 128 * 2);
    unsigned short* hbf = (unsigned short*)alloc((size_t)NN * TOT * 2);
    float* al     = (float*)alloc((size_t)NN * 4 * 4);
    float* ar     = (float*)alloc((size_t)NN * 4 * 4);
    int*   deg    = (int*)alloc((size_t)NN * 4);
    int*   rowptr = (int*)alloc((size_t)(NN + 1) * 4);
    int*   bsum   = (int*)alloc((size_t)512 * 4);
    int*   cursor = (int*)alloc((size_t)BKT * STRIPES * 4);
    int2*  tmp    = (int2*)alloc((size_t)BKT * STRIPES * CAPS * 8);
    int2*  rec    = (int2*)alloc((size_t)NE * 8);
    size_t needed = (size_t)(w - (char*)d_ws);
    if (ws_size < needed) return;  // fail loudly (validation will catch)

    hipMemsetAsync(cursor, 0, (size_t)BKT * STRIPES * 4, stream);

    k0_wt<<<(NCOL * 128 + 255) / 256, 256, 0, stream>>>(lw, lrw, attl, attr, WTh, WTl);
    k1_mfma<<<(NN + 127) / 128, 256, 0, stream>>>(x, WTh, WTl, hbf, out, al, ar);
    kbin2<<<NBIN, 512, 0, stream>>>(src, dst, ew, cursor, tmp);
    kdeg<<<BKT, 256, 0, stream>>>(cursor, tmp, deg);
    kscan_block<<<NB, 256, 0, stream>>>(deg, bsum);
    kscan_top<<<1, 512, 0, stream>>>(bsum);
    kscan_final<<<NB, 256, 0, stream>>>(deg, bsum, rowptr);
    kperm<<<BKT, 256, 0, stream>>>(cursor, tmp, rowptr, rec);
    kagg<<<(NN + 15) / 16, 256, 0, stream>>>(rowptr, rec, al, ar, hbf, out);
}

// Round 8
// 166.692 us; speedup vs baseline: 4.8566x; 1.0589x over previous
//
#include <hip/hip_runtime.h>
#include <float.h>

#define NN 100000
#define NE 1600000
#define IND 128
#define NH 4
#define TOT 64
#define NCOL 144                 // 64 h | 64 res | 4 al | 4 ar | 8 pad
#define BKT 782                  // ceil(NN/128): buckets of 128 dst nodes
#define STRIPES 8                // XCD stripes per bucket
#define CAPS 512                 // per (bucket,stripe) record capacity (mean 256, 16 sigma)
#define CHUNK 8192               // edges per kbin2 block
#define NBIN ((NE + CHUNK - 1) / CHUNK)   // 196
#define STRIDE 3072              // records per bucket in rec (mean 2048, >20 sigma)

typedef __attribute__((ext_vector_type(8))) short short8;
typedef __attribute__((ext_vector_type(4))) float f32x4;

__device__ __forceinline__ float lrelu(float a) { return a > 0.0f ? a : 0.2f * a; }

__device__ __forceinline__ unsigned short bf16_rne(float f) {
    unsigned u = __float_as_uint(f);
    unsigned r = u + 0x7FFFu + ((u >> 16) & 1u);
    return (unsigned short)(r >> 16);
}
__device__ __forceinline__ float bf16_to_f(unsigned short h) {
    return __uint_as_float(((unsigned)h) << 16);
}

// K0: build split-bf16 transposed weights WT[c][k], c in [0,144)
__global__ void k0_wt(const float* __restrict__ lw, const float* __restrict__ lrw,
                      const float* __restrict__ attl, const float* __restrict__ attr,
                      unsigned short* __restrict__ WTh, unsigned short* __restrict__ WTl) {
    int idx = blockIdx.x * 256 + threadIdx.x;   // NCOL*128 = 18432
    if (idx >= NCOL * 128) return;
    int c = idx >> 7, k = idx & 127;
    float v = 0.f;
    if (c < 64) v = lw[k * 64 + c];
    else if (c < 128) v = lrw[k * 64 + (c - 64)];
    else if (c < 132) {
        int hh = c - 128; float s = 0.f;
        #pragma unroll
        for (int j = 0; j < 16; ++j) s += lw[k * 64 + hh * 16 + j] * attl[hh * 16 + j];
        v = s;
    } else if (c < 136) {
        int hh = c - 132; float s = 0.f;
        #pragma unroll
        for (int j = 0; j < 16; ++j) s += lw[k * 64 + hh * 16 + j] * attr[hh * 16 + j];
        v = s;
    }
    unsigned short hi = bf16_rne(v);
    float hif = bf16_to_f(hi);
    WTh[idx] = hi;
    WTl[idx] = bf16_rne(v - hif);
}

// K1: MFMA GEMM, x[100000x128] @ WT^T[128x144] via split-bf16 (3 mfma per tile)
__global__ __launch_bounds__(256) void k1_mfma(const float* __restrict__ x,
        const unsigned short* __restrict__ WTh, const unsigned short* __restrict__ WTl,
        unsigned short* __restrict__ hbf, float* __restrict__ res,
        float* __restrict__ al, float* __restrict__ ar) {
    int lane = threadIdx.x & 63;
    int wave = threadIdx.x >> 6;
    int row0 = blockIdx.x * 128 + wave * 32;
    int lr = lane & 15;     // A-row / B-col / C-col within tile
    int lk = lane >> 4;     // k-group (0..3)

    f32x4 acc[2][9];
    #pragma unroll
    for (int mt = 0; mt < 2; ++mt)
        #pragma unroll
        for (int nt = 0; nt < 9; ++nt) acc[mt][nt] = (f32x4)(0.f);

    #pragma unroll
    for (int ks = 0; ks < 4; ++ks) {
        int k0 = ks * 32 + lk * 8;
        short8 bh[9], bl[9];
        #pragma unroll
        for (int nt = 0; nt < 9; ++nt) {
            bh[nt] = *(const short8*)(WTh + (size_t)(nt * 16 + lr) * 128 + k0);
            bl[nt] = *(const short8*)(WTl + (size_t)(nt * 16 + lr) * 128 + k0);
        }
        #pragma unroll
        for (int mt = 0; mt < 2; ++mt) {
            int row = row0 + mt * 16 + lr;
            float4 v0 = make_float4(0.f, 0.f, 0.f, 0.f), v1 = v0;
            if (row < NN) {
                v0 = *(const float4*)(x + (size_t)row * IND + k0);
                v1 = *(const float4*)(x + (size_t)row * IND + k0 + 4);
            }
            float vs[8] = {v0.x, v0.y, v0.z, v0.w, v1.x, v1.y, v1.z, v1.w};
            short8 ah, alo;
            #pragma unroll
            for (int i = 0; i < 8; ++i) {
                unsigned short hi = bf16_rne(vs[i]);
                ah[i] = (short)hi;
                alo[i] = (short)bf16_rne(vs[i] - bf16_to_f(hi));
            }
            #pragma unroll
            for (int nt = 0; nt < 9; ++nt) {
                acc[mt][nt] = __builtin_amdgcn_mfma_f32_16x16x32_bf16(ah, bh[nt], acc[mt][nt], 0, 0, 0);
                acc[mt][nt] = __builtin_amdgcn_mfma_f32_16x16x32_bf16(alo, bh[nt], acc[mt][nt], 0, 0, 0);
                acc[mt][nt] = __builtin_amdgcn_mfma_f32_16x16x32_bf16(ah, bl[nt], acc[mt][nt], 0, 0, 0);
            }
        }
    }
    #pragma unroll
    for (int mt = 0; mt < 2; ++mt) {
        #pragma unroll
        for (int nt = 0; nt < 9; ++nt) {
            int c = nt * 16 + lr;
            #pragma unroll
            for (int r = 0; r < 4; ++r) {
                int row = row0 + mt * 16 + lk * 4 + r;
                if (row >= NN) continue;
                float v = acc[mt][nt][r];
                if (c < 64)       hbf[(size_t)row * TOT + c] = bf16_rne(v);
                else if (c < 128) res[(size_t)row * TOT + (c - 64)] = v;
                else if (c < 132) al[(size_t)row * 4 + (c - 128)] = v;
                else if (c < 136) ar[(size_t)row * 4 + (c - 132)] = v;
            }
        }
    }
}

// kbin2: chunked counting-append. Each block owns CHUNK edges: LDS histogram over
// the 782 buckets -> one global atomicAdd per nonempty bucket reserves a RUN
// (mean ~10.5 records) in that bucket's stripe region -> re-read chunk (L2-hot)
// and write records into the run. Long runs -> full-line writebacks.
__global__ __launch_bounds__(512) void kbin2(const int* __restrict__ src,
                                             const int* __restrict__ dst,
                                             const float* __restrict__ ew,
                                             int* __restrict__ cursor,
                                             int2* __restrict__ tmp) {
    __shared__ int hist[BKT];
    __shared__ int lcur[BKT];
    int tid = threadIdx.x;
    int stripe = blockIdx.x & 7;
    int e0 = blockIdx.x * CHUNK;
    for (int i = tid; i < BKT; i += 512) hist[i] = 0;
    __syncthreads();
    for (int i = tid; i < CHUNK; i += 512) {
        int e = e0 + i;
        if (e < NE) atomicAdd(&hist[dst[e] >> 7], 1);
    }
    __syncthreads();
    for (int b = tid; b < BKT; b += 512) {
        int c = hist[b];
        lcur[b] = (c > 0) ? atomicAdd(cursor + b * STRIPES + stripe, c) : 0;
    }
    __syncthreads();
    for (int i = tid; i < CHUNK; i += 512) {
        int e = e0 + i;
        if (e >= NE) continue;
        int d = dst[e];
        int b = d >> 7;
        int pos = atomicAdd(&lcur[b], 1);
        if (pos < CAPS)
            tmp[(size_t)(b * STRIPES + stripe) * CAPS + pos] =
                make_int2(src[e] | ((d & 127) << 20), __float_as_int(ew[e]));
    }
}

// kperm2: one block per bucket. LDS histogram over the bucket's stripes ->
// 129-wide LDS scan -> local rowptr (written to rowptrL) -> scatter tmp into
// bucket-strided rec at local offsets. Replaces kdeg + 3 scan kernels + kperm.
__global__ __launch_bounds__(256) void kperm2(const int* __restrict__ cursor,
                                              const int2* __restrict__ tmp,
                                              int* __restrict__ rowptrL,
                                              int2* __restrict__ rec) {
    __shared__ int hist[129];
    __shared__ int cur[128];
    int tid = threadIdx.x;
    int b = blockIdx.x;
    if (tid < 129) hist[tid] = 0;
    __syncthreads();
    // pass 1: counts (hist[dlo+1] so the scan yields exclusive offsets)
    #pragma unroll
    for (int s8 = 0; s8 < STRIPES; ++s8) {
        int sb = b * STRIPES + s8;
        int n = min(cursor[sb], CAPS);
        const int2* tp = tmp + (size_t)sb * CAPS;
        for (int i = tid; i < n; i += 256)
            atomicAdd(&hist[(((unsigned)tp[i].x) >> 20) + 1], 1);
    }
    __syncthreads();
    // Hillis-Steele inclusive scan over hist[0..128] (orig hist[0]=0 ->
    // result: hist[i] = exclusive prefix of degrees up to node i)
    for (int off = 1; off < 129; off <<= 1) {
        int v = 0;
        if (tid < 129 && tid >= off) v = hist[tid - off];
        __syncthreads();
        if (tid < 129) hist[tid] += v;
        __syncthreads();
    }
    if (tid < 129) rowptrL[b * 129 + tid] = hist[tid];
    if (tid < 128) cur[tid] = hist[tid];
    __syncthreads();
    // pass 2: scatter into bucket-strided rec (write window ~16KB, L2-local)
    #pragma unroll
    for (int s8 = 0; s8 < STRIPES; ++s8) {
        int sb = b * STRIPES + s8;
        int n = min(cursor[sb], CAPS);
        const int2* tp = tmp + (size_t)sb * CAPS;
        for (int i = tid; i < n; i += 256) {
            int2 r = tp[i];
            int dlo = ((unsigned)r.x) >> 20;
            int pos = atomicAdd(&cur[dlo], 1);
            if (pos < STRIDE)
                rec[(size_t)b * STRIDE + pos] = make_int2(r.x & 0xFFFFF, r.y);
        }
    }
}

// Aggregate per node, SINGLE pass, register accumulation, no atomics:
// agg = sum(exp(a_e) * h[src_e]) / sum(exp(a_e))   (softmax shift-invariance,
// |a| <~ 4 so no max subtraction needed). Then ELU + residual (already in out).
__global__ __launch_bounds__(256) void kagg(const int* __restrict__ rowptrL,
                                            const int2* __restrict__ rec,
                                            const float* __restrict__ al,
                                            const float* __restrict__ ar,
                                            const unsigned short* __restrict__ hbf,
                                            float* __restrict__ out) {
    int t = threadIdx.x;
    int node = blockIdx.x * 16 + (t >> 4);
    if (node >= NN) return;
    int part = t & 15;
    int head = part >> 2;
    int b = node >> 7, dlo = node & 127;
    int beg = rowptrL[b * 129 + dlo];
    int end = min(rowptrL[b * 129 + dlo + 1], STRIDE);
    beg = min(beg, end);
    const int2* rp = rec + (size_t)b * STRIDE;
    float arh = ar[(size_t)node * 4 + head];

    float4 acc = make_float4(0.f, 0.f, 0.f, 0.f);
    float den = 0.f;
    for (int p = beg; p < end; ++p) {
        int2 r = rp[p];                        // broadcast across 16 lanes
        int s = r.x;
        float w = __int_as_float(r.y);
        float a = lrelu(w * (al[(size_t)s * 4 + head] + arh));
        float c = __expf(a);
        den += c;
        uint2 u = *(const uint2*)(hbf + (size_t)s * TOT + part * 4);  // 4 bf16 = 8B
        float h0 = __uint_as_float(u.x << 16);
        float h1 = __uint_as_float(u.x & 0xFFFF0000u);
        float h2 = __uint_as_float(u.y << 16);
        float h3 = __uint_as_float(u.y & 0xFFFF0000u);
        acc.x = fmaf(h0, c, acc.x);
        acc.y = fmaf(h1, c, acc.y);
        acc.z = fmaf(h2, c, acc.z);
        acc.w = fmaf(h3, c, acc.w);
    }
    float rinv = (den > 0.f) ? 1.f / den : 0.f;
    acc.x *= rinv; acc.y *= rinv; acc.z *= rinv; acc.w *= rinv;

    float* op = out + (size_t)node * TOT + part * 4;
    float4 r = *(const float4*)op;
    float4 o;
    o.x = (acc.x > 0.f ? acc.x : expm1f(acc.x)) + r.x;
    o.y = (acc.y > 0.f ? acc.y : expm1f(acc.y)) + r.y;
    o.z = (acc.z > 0.f ? acc.z : expm1f(acc.z)) + r.z;
    o.w = (acc.w > 0.f ? acc.w : expm1f(acc.w)) + r.w;
    *(float4*)op = o;
}

extern "C" void kernel_launch(void* const* d_in, const int* in_sizes, int n_in,
                              void* d_out, int out_size, void* d_ws, size_t ws_size,
                              hipStream_t stream) {
    const float* x    = (const float*)d_in[0];
    const int*   ei   = (const int*)d_in[1];
    const float* ew   = (const float*)d_in[2];
    const float* lw   = (const float*)d_in[3];
    const float* attl = (const float*)d_in[4];
    const float* attr = (const float*)d_in[5];
    const float* lrw  = (const float*)d_in[6];
    float* out = (float*)d_out;
    const int* src = ei;
    const int* dst = ei + NE;

    char* w = (char*)d_ws;
    auto alloc = [&](size_t bytes) { char* p = w; w += (bytes + 255) & ~(size_t)255; return p; };
    unsigned short* WTh = (unsigned short*)alloc((size_t)NCOL * 128 * 2);
    unsigned short* WTl = (unsigned short*)alloc((size_t)NCOL * 128 * 2);
    unsigned short* hbf = (unsigned short*)alloc((size_t)NN * TOT * 2);
    float* al      = (float*)alloc((size_t)NN * 4 * 4);
    float* ar      = (float*)alloc((size_t)NN * 4 * 4);
    int*   rowptrL = (int*)alloc((size_t)BKT * 129 * 4);
    int*   cursor  = (int*)alloc((size_t)BKT * STRIPES * 4);
    int2*  tmp     = (int2*)alloc((size_t)BKT * STRIPES * CAPS * 8);
    int2*  rec     = (int2*)alloc((size_t)BKT * STRIDE * 8);
    size_t needed = (size_t)(w - (char*)d_ws);
    if (ws_size < needed) return;  // fail loudly (validation will catch)

    hipMemsetAsync(cursor, 0, (size_t)BKT * STRIPES * 4, stream);

    k0_wt<<<(NCOL * 128 + 255) / 256, 256, 0, stream>>>(lw, lrw, attl, attr, WTh, WTl);
    k1_mfma<<<(NN + 127) / 128, 256, 0, stream>>>(x, WTh, WTl, hbf, out, al, ar);
    kbin2<<<NBIN, 512, 0, stream>>>(src, dst, ew, cursor, tmp);
    kperm2<<<BKT, 256, 0, stream>>>(cursor, tmp, rowptrL, rec);
    kagg<<<(NN + 15) / 16, 256, 0, stream>>>(rowptrL, rec, al, ar, hbf, out);
}